// Round 3
// baseline (35.905 us; speedup 1.0000x reference)
//
#include <hip/hip_runtime.h>
#include <math.h>

// Spline geometry (uniform knots): lo = -18, dist = 36/29, 1/dist = 29/36
#define SP_INV_DIST (29.0f / 36.0f)
#define SP_U_OFFS   (17.5f)              // 3 - lo/dist
#define NEG_HALF_LOG_2PI (-0.91893853320467274f)

typedef float f32x4 __attribute__((ext_vector_type(4)));

// ---------------------------------------------------------------------------
// Per-element: clamp -> span -> ONE LDS float4 gather -> Horner (val + deriv)
// deriv poly is the analytic derivative of the value cubic: no second table.
// ---------------------------------------------------------------------------
__device__ __forceinline__ float eval_one(float xin, const float4* __restrict__ tab) {
    float x = fminf(fmaxf(xin, -15.0f), 15.0f);
    float u = fmaf(x, SP_INV_DIST, SP_U_OFFS);      // in [5.41, 29.59] -> s in [5,29]
    int   s = (int)u;
    float f = u - (float)s;
    float4 a = tab[s];
    float val = fmaf(fmaf(fmaf(a.w, f, a.z), f, a.y), f, a.x);
    float der = fmaf(f, fmaf(f, 3.0f * a.w, 2.0f * a.z), a.y) * SP_INV_DIST;
    return fmaf(-0.5f * val, val, NEG_HALF_LOG_2PI) + __logf(der);
}

// ---------------------------------------------------------------------------
// Single fused kernel: wave 0 of each block builds the 32-entry power-basis
// table (softplus + shfl-scan cumsum + cubic->power conversion), then all
// 256 threads stream 4 independent float4s each (nontemporal in/out).
// ---------------------------------------------------------------------------
__global__ __launch_bounds__(256) void TM_73727408603569_kernel(
        const float* __restrict__ y, const float* __restrict__ params,
        float* __restrict__ out, int n4, int tail_base, int tail) {
    __shared__ float4 tab[32];
    int t = threadIdx.x;

    if (t < 64) {                       // wave 0 only: build table
        bool lane_p = (t >= 1 && t < 32);
        float p  = lane_p ? params[t] : 0.0f;
        float sp = lane_p ? ((p > 0.0f) ? (p + log1pf(expf(-p)))
                                        : log1pf(expf(p)))
                          : 0.0f;
        #pragma unroll
        for (int d = 1; d < 32; d <<= 1) {      // inclusive scan (all 64 lanes)
            float o = __shfl_up(sp, d, 64);
            if (t >= d) sp += o;
        }
        float c  = params[0] + sp;              // c[t] = monotonic coef t
        float d0 = __shfl_up(c, 3, 64);
        float d1 = __shfl_up(c, 2, 64);
        float d2 = __shfl_up(c, 1, 64);
        float d3 = c;
        if (t < 32) {
            float4 vp = make_float4(0.f, 0.f, 0.f, 0.f);
            if (t >= 3) {                        // B-spline -> power basis in f
                const float SIXTH = 1.0f / 6.0f;
                vp.x = (d0 + 4.0f * d1 + d2) * SIXTH;
                vp.y = (d2 - d0) * 0.5f;
                vp.z = (d0 - 2.0f * d1 + d2) * 0.5f;
                vp.w = (d3 - d0 + 3.0f * (d1 - d2)) * SIXTH;
            }
            tab[t] = vp;
        }
    }
    __syncthreads();

    const f32x4* y4 = reinterpret_cast<const f32x4*>(y);
    f32x4*       o4 = reinterpret_cast<f32x4*>(out);

    int i0 = blockIdx.x * 1024 + t;
    int i1 = i0 + 256, i2 = i0 + 512, i3 = i0 + 768;
    bool p0 = i0 < n4, p1 = i1 < n4, p2 = i2 < n4, p3 = i3 < n4;
    f32x4 v0, v1, v2, v3;
    if (p0) v0 = __builtin_nontemporal_load(&y4[i0]);
    if (p1) v1 = __builtin_nontemporal_load(&y4[i1]);
    if (p2) v2 = __builtin_nontemporal_load(&y4[i2]);
    if (p3) v3 = __builtin_nontemporal_load(&y4[i3]);

    if (p0) {
        f32x4 r;
        r.x = eval_one(v0.x, tab); r.y = eval_one(v0.y, tab);
        r.z = eval_one(v0.z, tab); r.w = eval_one(v0.w, tab);
        __builtin_nontemporal_store(r, &o4[i0]);
    }
    if (p1) {
        f32x4 r;
        r.x = eval_one(v1.x, tab); r.y = eval_one(v1.y, tab);
        r.z = eval_one(v1.z, tab); r.w = eval_one(v1.w, tab);
        __builtin_nontemporal_store(r, &o4[i1]);
    }
    if (p2) {
        f32x4 r;
        r.x = eval_one(v2.x, tab); r.y = eval_one(v2.y, tab);
        r.z = eval_one(v2.z, tab); r.w = eval_one(v2.w, tab);
        __builtin_nontemporal_store(r, &o4[i2]);
    }
    if (p3) {
        f32x4 r;
        r.x = eval_one(v3.x, tab); r.y = eval_one(v3.y, tab);
        r.z = eval_one(v3.z, tab); r.w = eval_one(v3.w, tab);
        __builtin_nontemporal_store(r, &o4[i3]);
    }

    // scalar tail (n not multiple of 4)
    if (blockIdx.x == 0 && t < tail) {
        int idx = tail_base + t;
        out[idx] = eval_one(y[idx], tab);
    }
}

extern "C" void kernel_launch(void* const* d_in, const int* in_sizes, int n_in,
                              void* d_out, int out_size, void* d_ws, size_t ws_size,
                              hipStream_t stream) {
    const float* params = (const float*)d_in[0];
    const float* y      = (const float*)d_in[1];
    float*       out    = (float*)d_out;
    int n    = in_sizes[1];
    int n4   = n >> 2;
    int tail = n & 3;

    int blocks = (n4 + 1023) / 1024;
    if (blocks < 1) blocks = 1;
    TM_73727408603569_kernel<<<blocks, 256, 0, stream>>>(y, params, out, n4,
                                                         n4 << 2, tail);
}

// Round 4
// 35.497 us; speedup vs baseline: 1.0115x; 1.0115x over previous
//
#include <hip/hip_runtime.h>
#include <math.h>

// Spline geometry (uniform knots): lo = -18, dist = 36/29, 1/dist = 29/36
#define SP_INV_DIST (29.0f / 36.0f)
#define SP_U_OFFS   (17.5f)              // 3 - lo/dist
#define NEG_HALF_LOG_2PI (-0.91893853320467274f)

typedef float f32x4 __attribute__((ext_vector_type(4)));

// ---------------------------------------------------------------------------
// Per-element: clamp -> span -> ONE LDS float4 gather -> Horner (val + deriv)
// deriv poly is the analytic derivative of the value cubic (no second table).
// ---------------------------------------------------------------------------
__device__ __forceinline__ float eval_one(float xin, const float4* __restrict__ tab) {
    float x = fminf(fmaxf(xin, -15.0f), 15.0f);
    float u = fmaf(x, SP_INV_DIST, SP_U_OFFS);      // in [5.41, 29.59] -> s in [5,29]
    int   s = (int)u;
    float f = u - (float)s;
    float4 a = tab[s];
    float val = fmaf(fmaf(fmaf(a.w, f, a.z), f, a.y), f, a.x);
    float der = fmaf(f, fmaf(f, 3.0f * a.w, 2.0f * a.z), a.y) * SP_INV_DIST;
    return fmaf(-0.5f * val, val, NEG_HALF_LOG_2PI) + __logf(der);
}

// ---------------------------------------------------------------------------
// Single fused kernel: wave 0 of each block builds the 32-entry power-basis
// table (softplus + shfl-scan cumsum + B-spline->power conversion), then all
// 256 threads stream 4 independent float4s each (plain loads/stores: the
// 160 MB working set is L3-resident across replays — do NOT bypass cache).
// ---------------------------------------------------------------------------
__global__ __launch_bounds__(256) void TM_73727408603569_kernel(
        const float* __restrict__ y, const float* __restrict__ params,
        float* __restrict__ out, int n4, int tail_base, int tail) {
    __shared__ float4 tab[32];
    int t = threadIdx.x;

    if (t < 64) {                       // wave 0 only: build table
        bool lane_p = (t >= 1 && t < 32);
        float p  = lane_p ? params[t] : 0.0f;
        float sp = lane_p ? ((p > 0.0f) ? (p + log1pf(expf(-p)))
                                        : log1pf(expf(p)))
                          : 0.0f;
        #pragma unroll
        for (int d = 1; d < 32; d <<= 1) {      // inclusive scan across lanes
            float o = __shfl_up(sp, d, 64);
            if (t >= d) sp += o;
        }
        float c  = params[0] + sp;              // c[t] = monotonic coef t
        float d0 = __shfl_up(c, 3, 64);
        float d1 = __shfl_up(c, 2, 64);
        float d2 = __shfl_up(c, 1, 64);
        float d3 = c;
        if (t < 32) {
            float4 vp = make_float4(0.f, 0.f, 0.f, 0.f);
            if (t >= 3) {                        // B-spline -> power basis in f
                const float SIXTH = 1.0f / 6.0f;
                vp.x = (d0 + 4.0f * d1 + d2) * SIXTH;
                vp.y = (d2 - d0) * 0.5f;
                vp.z = (d0 - 2.0f * d1 + d2) * 0.5f;
                vp.w = (d3 - d0 + 3.0f * (d1 - d2)) * SIXTH;
            }
            tab[t] = vp;
        }
    }
    __syncthreads();

    const f32x4* y4 = reinterpret_cast<const f32x4*>(y);
    f32x4*       o4 = reinterpret_cast<f32x4*>(out);

    int i0 = blockIdx.x * 1024 + t;
    int i1 = i0 + 256, i2 = i0 + 512, i3 = i0 + 768;
    bool p0 = i0 < n4, p1 = i1 < n4, p2 = i2 < n4, p3 = i3 < n4;
    f32x4 v0, v1, v2, v3;
    if (p0) v0 = y4[i0];
    if (p1) v1 = y4[i1];
    if (p2) v2 = y4[i2];
    if (p3) v3 = y4[i3];               // all 4 loads in flight before dep chains

    if (p0) {
        f32x4 r;
        r.x = eval_one(v0.x, tab); r.y = eval_one(v0.y, tab);
        r.z = eval_one(v0.z, tab); r.w = eval_one(v0.w, tab);
        o4[i0] = r;
    }
    if (p1) {
        f32x4 r;
        r.x = eval_one(v1.x, tab); r.y = eval_one(v1.y, tab);
        r.z = eval_one(v1.z, tab); r.w = eval_one(v1.w, tab);
        o4[i1] = r;
    }
    if (p2) {
        f32x4 r;
        r.x = eval_one(v2.x, tab); r.y = eval_one(v2.y, tab);
        r.z = eval_one(v2.z, tab); r.w = eval_one(v2.w, tab);
        o4[i2] = r;
    }
    if (p3) {
        f32x4 r;
        r.x = eval_one(v3.x, tab); r.y = eval_one(v3.y, tab);
        r.z = eval_one(v3.z, tab); r.w = eval_one(v3.w, tab);
        o4[i3] = r;
    }

    // scalar tail (n not multiple of 4)
    if (blockIdx.x == 0 && t < tail) {
        int idx = tail_base + t;
        out[idx] = eval_one(y[idx], tab);
    }
}

extern "C" void kernel_launch(void* const* d_in, const int* in_sizes, int n_in,
                              void* d_out, int out_size, void* d_ws, size_t ws_size,
                              hipStream_t stream) {
    const float* params = (const float*)d_in[0];
    const float* y      = (const float*)d_in[1];
    float*       out    = (float*)d_out;
    int n    = in_sizes[1];
    int n4   = n >> 2;
    int tail = n & 3;

    int blocks = (n4 + 1023) / 1024;
    if (blocks < 1) blocks = 1;
    TM_73727408603569_kernel<<<blocks, 256, 0, stream>>>(y, params, out, n4,
                                                         n4 << 2, tail);
}

// Round 5
// 31.323 us; speedup vs baseline: 1.1463x; 1.1333x over previous
//
#include <hip/hip_runtime.h>
#include <math.h>

// Spline geometry (uniform knots): lo = -18, dist = 36/29, 1/dist = 29/36
#define SP_INV_DIST (29.0f / 36.0f)
#define SP_U_OFFS   (17.5f)              // 3 - lo/dist
// -0.5*log(2*pi) + log(1/dist):  -0.91893853320467274 + log(29/36)
#define C_CONST (-1.13516164467f)

typedef float f32x4 __attribute__((ext_vector_type(4)));

// ---------------------------------------------------------------------------
// Per-element: clamp -> span -> ONE LDS float4 gather -> Horner (val + deriv)
// deriv scale 1/dist is folded into the additive constant (log is additive).
// ---------------------------------------------------------------------------
__device__ __forceinline__ float eval_one(float xin, const float4* __restrict__ tab) {
    float x = __builtin_amdgcn_fmed3f(xin, -15.0f, 15.0f);   // clamp, 1 inst
    float u = fmaf(x, SP_INV_DIST, SP_U_OFFS);               // in [5.41, 29.59]
    int   s = (int)u;
    float f = u - (float)s;
    float4 a = tab[s];
    float val = fmaf(fmaf(fmaf(a.w, f, a.z), f, a.y), f, a.x);
    float der = fmaf(f, fmaf(f, 3.0f * a.w, a.z + a.z), a.y); // d(val)/df (>0)
    return fmaf(-0.5f * val, val, C_CONST) + __logf(der);
}

__device__ __forceinline__ f32x4 eval4(f32x4 v, const float4* __restrict__ tab) {
    f32x4 r;
    r.x = eval_one(v.x, tab); r.y = eval_one(v.y, tab);
    r.z = eval_one(v.z, tab); r.w = eval_one(v.w, tab);
    return r;
}

// ---------------------------------------------------------------------------
// Persistent software-pipelined streamer. 2048 blocks x 256 thr (8 blk/CU,
// full residency). Each iteration: issue NEXT pair of float4 loads, then
// evaluate+store CURRENT pair -> global loads stay outstanding continuously
// (fixes the bursty one-shot duty cycle that capped BW at ~50%).
// ---------------------------------------------------------------------------
__global__ __launch_bounds__(256) void TM_73727408603569_kernel(
        const float* __restrict__ y, const float* __restrict__ params,
        float* __restrict__ out, int n4, int tail_base, int tail) {
    __shared__ float4 tab[32];
    int t = threadIdx.x;

    if (t < 64) {                       // wave 0 only: build table
        bool lane_p = (t >= 1 && t < 32);
        float p  = lane_p ? params[t] : 0.0f;
        float sp = lane_p ? ((p > 0.0f) ? (p + log1pf(expf(-p)))
                                        : log1pf(expf(p)))
                          : 0.0f;
        #pragma unroll
        for (int d = 1; d < 32; d <<= 1) {      // inclusive scan across lanes
            float o = __shfl_up(sp, d, 64);
            if (t >= d) sp += o;
        }
        float c  = params[0] + sp;              // monotonic coef t
        float d0 = __shfl_up(c, 3, 64);
        float d1 = __shfl_up(c, 2, 64);
        float d2 = __shfl_up(c, 1, 64);
        float d3 = c;
        if (t < 32) {
            float4 vp = make_float4(0.f, 0.f, 0.f, 0.f);
            if (t >= 3) {                        // B-spline -> power basis in f
                const float SIXTH = 1.0f / 6.0f;
                vp.x = (d0 + 4.0f * d1 + d2) * SIXTH;
                vp.y = (d2 - d0) * 0.5f;
                vp.z = (d0 - 2.0f * d1 + d2) * 0.5f;
                vp.w = (d3 - d0 + 3.0f * (d1 - d2)) * SIXTH;
            }
            tab[t] = vp;
        }
    }
    __syncthreads();

    const f32x4* y4 = reinterpret_cast<const f32x4*>(y);
    f32x4*       o4 = reinterpret_cast<f32x4*>(out);

    const int S    = gridDim.x << 9;            // stride: blocks * 512 float4
    const int bb   = blockIdx.x << 9;           // this block's first slot
    // #sweeps this block participates in (block-uniform; >=0)
    int niter = (n4 > bb) ? ((n4 - 1 - bb) / S + 1) : 0;

    int  i0 = bb + t, i1 = i0 + 256;
    bool q0 = i0 < n4, q1 = i1 < n4;
    f32x4 c0, c1;
    if (niter > 0) {
        if (q0) c0 = y4[i0];
        if (q1) c1 = y4[i1];
        for (int k = 1; k < niter; ++k) {
            int  j0 = i0 + S, j1 = i1 + S;
            bool r0 = j0 < n4, r1 = j1 < n4;
            f32x4 nx0, nx1;
            if (r0) nx0 = y4[j0];               // prefetch next sweep
            if (r1) nx1 = y4[j1];
            if (q0) o4[i0] = eval4(c0, tab);    // finish current sweep
            if (q1) o4[i1] = eval4(c1, tab);
            i0 = j0; i1 = j1; q0 = r0; q1 = r1; c0 = nx0; c1 = nx1;
        }
        if (q0) o4[i0] = eval4(c0, tab);
        if (q1) o4[i1] = eval4(c1, tab);
    }

    // scalar tail (n not multiple of 4)
    if (blockIdx.x == 0 && t < tail) {
        int idx = tail_base + t;
        out[idx] = eval_one(y[idx], tab);
    }
}

extern "C" void kernel_launch(void* const* d_in, const int* in_sizes, int n_in,
                              void* d_out, int out_size, void* d_ws, size_t ws_size,
                              hipStream_t stream) {
    const float* params = (const float*)d_in[0];
    const float* y      = (const float*)d_in[1];
    float*       out    = (float*)d_out;
    int n    = in_sizes[1];
    int n4   = n >> 2;
    int tail = n & 3;

    int blocks = (n4 + 511) / 512;
    if (blocks > 2048) blocks = 2048;
    if (blocks < 1) blocks = 1;
    TM_73727408603569_kernel<<<blocks, 256, 0, stream>>>(y, params, out, n4,
                                                         n4 << 2, tail);
}

// Round 6
// 29.779 us; speedup vs baseline: 1.2057x; 1.0519x over previous
//
#include <hip/hip_runtime.h>
#include <math.h>

// Spline geometry (uniform knots): lo = -18, dist = 36/29, 1/dist = 29/36
#define SP_INV_DIST (29.0f / 36.0f)
#define SP_U_OFFS   (17.5f)              // 3 - lo/dist
// -0.5*log(2*pi) + log(1/dist) : log of deriv's 1/dist folded in additively
#define C_CONST (-1.13516164467f)
#define LN2 (0.69314718056f)

typedef float f32x4 __attribute__((ext_vector_type(4)));

// ---------------------------------------------------------------------------
// Per-element: clamp -> span -> TWO LDS float4 reads off ONE address
// (value cubic at tab[s], derivative quadratic at tab[s+32] -> offset:512
// immediate, zero extra addressing) -> Horner -> logprob.
// ---------------------------------------------------------------------------
__device__ __forceinline__ float eval_one(float xin, const float4* __restrict__ tab) {
    float x = __builtin_amdgcn_fmed3f(xin, -15.0f, 15.0f);   // clamp, 1 inst
    float u = fmaf(x, SP_INV_DIST, SP_U_OFFS);               // in [5.41, 29.59]
    int   s = (int)u;
#if __has_builtin(__builtin_amdgcn_fractf)
    float f = __builtin_amdgcn_fractf(u);                    // u>0: fract==frac
#else
    float f = u - (float)s;
#endif
    float4 a = tab[s];
    float4 q = tab[s + 32];                                  // same addr +512B
    float val = fmaf(fmaf(fmaf(a.w, f, a.z), f, a.y), f, a.x);
    float der = fmaf(fmaf(q.z, f, q.y), f, q.x);             // d(val)/df  (>0)
    float l2  = __log2f(der);                                // raw v_log_f32
    return fmaf(LN2, l2, fmaf(-0.5f * val, val, C_CONST));
}

__device__ __forceinline__ f32x4 eval4(f32x4 v, const float4* __restrict__ tab) {
    f32x4 r;
    r.x = eval_one(v.x, tab); r.y = eval_one(v.y, tab);
    r.z = eval_one(v.z, tab); r.w = eval_one(v.w, tab);
    return r;
}

// ---------------------------------------------------------------------------
// Persistent software-pipelined streamer. 2048 blocks x 256 thr (8 blk/CU,
// full 32-wave residency). Each iteration: issue NEXT pair of float4 loads,
// then evaluate+store CURRENT pair -> loads stay outstanding continuously.
// ---------------------------------------------------------------------------
__global__ __launch_bounds__(256) void TM_73727408603569_kernel(
        const float* __restrict__ y, const float* __restrict__ params,
        float* __restrict__ out, int n4, int tail_base, int tail) {
    __shared__ float4 tab[64];          // [0..31] value poly, [32..63] deriv poly
    int t = threadIdx.x;

    if (t < 64) {                       // wave 0 only: build tables
        bool lane_p = (t >= 1 && t < 32);
        float p  = lane_p ? params[t] : 0.0f;
        float sp = lane_p ? ((p > 0.0f) ? (p + log1pf(expf(-p)))
                                        : log1pf(expf(p)))
                          : 0.0f;
        #pragma unroll
        for (int d = 1; d < 32; d <<= 1) {      // inclusive scan across lanes
            float o = __shfl_up(sp, d, 64);
            if (t >= d) sp += o;
        }
        float c  = params[0] + sp;              // monotonic coef t
        float d0 = __shfl_up(c, 3, 64);
        float d1 = __shfl_up(c, 2, 64);
        float d2 = __shfl_up(c, 1, 64);
        float d3 = c;
        if (t < 32) {
            float4 vp = make_float4(0.f, 0.f, 0.f, 0.f);
            float4 dp = make_float4(0.f, 0.f, 0.f, 0.f);
            if (t >= 3) {                        // B-spline -> power basis in f
                const float SIXTH = 1.0f / 6.0f;
                vp.x = (d0 + 4.0f * d1 + d2) * SIXTH;
                vp.y = (d2 - d0) * 0.5f;
                vp.z = (d0 - 2.0f * d1 + d2) * 0.5f;
                vp.w = (d3 - d0 + 3.0f * (d1 - d2)) * SIXTH;
                dp.x = vp.y;                     // a1
                dp.y = vp.z + vp.z;              // 2*a2
                dp.z = 3.0f * vp.w;              // 3*a3
            }
            tab[t]      = vp;
            tab[32 + t] = dp;
        }
    }
    __syncthreads();

    const f32x4* y4 = reinterpret_cast<const f32x4*>(y);
    f32x4*       o4 = reinterpret_cast<f32x4*>(out);

    const int S  = gridDim.x << 9;              // stride: blocks * 512 float4
    const int bb = blockIdx.x << 9;             // this block's first slot
    int niter = (n4 > bb) ? ((n4 - 1 - bb) / S + 1) : 0;   // block-uniform

    int  i0 = bb + t, i1 = i0 + 256;
    bool q0 = i0 < n4, q1 = i1 < n4;
    f32x4 c0, c1;
    if (niter > 0) {
        if (q0) c0 = y4[i0];
        if (q1) c1 = y4[i1];
        for (int k = 1; k < niter; ++k) {
            int  j0 = i0 + S, j1 = i1 + S;
            bool r0 = j0 < n4, r1 = j1 < n4;
            f32x4 nx0, nx1;
            if (r0) nx0 = y4[j0];               // prefetch next sweep
            if (r1) nx1 = y4[j1];
            if (q0) o4[i0] = eval4(c0, tab);    // finish current sweep
            if (q1) o4[i1] = eval4(c1, tab);
            i0 = j0; i1 = j1; q0 = r0; q1 = r1; c0 = nx0; c1 = nx1;
        }
        if (q0) o4[i0] = eval4(c0, tab);
        if (q1) o4[i1] = eval4(c1, tab);
    }

    // scalar tail (n not multiple of 4)
    if (blockIdx.x == 0 && t < tail) {
        int idx = tail_base + t;
        out[idx] = eval_one(y[idx], tab);
    }
}

extern "C" void kernel_launch(void* const* d_in, const int* in_sizes, int n_in,
                              void* d_out, int out_size, void* d_ws, size_t ws_size,
                              hipStream_t stream) {
    const float* params = (const float*)d_in[0];
    const float* y      = (const float*)d_in[1];
    float*       out    = (float*)d_out;
    int n    = in_sizes[1];
    int n4   = n >> 2;
    int tail = n & 3;

    int blocks = (n4 + 511) / 512;
    if (blocks > 2048) blocks = 2048;
    if (blocks < 1) blocks = 1;
    TM_73727408603569_kernel<<<blocks, 256, 0, stream>>>(y, params, out, n4,
                                                         n4 << 2, tail);
}